// Round 7
// baseline (493.187 us; speedup 1.0000x reference)
//
#include <hip/hip_runtime.h>
#include <hip/hip_fp16.h>
#include <stdint.h>

// GCN 2-layer forward: two-level counting sort -> dst-sorted CSR -> pull gathers.
// gather1: half2 channel-pairs, 2 edge-slots per group (16 edges in flight),
// nontemporal csr/drop_u. gemm: W1 in LDS, 8 rows in flight (4 ds_read : 32 FMA).

#define TPB 256
#define TILE 512           // nodes per bucket
#define TSH  9
#define MAXB 512           // supports N <= 262144 (src must fit 18 bits)

typedef float f2v __attribute__((ext_vector_type(2)));
typedef float f4v __attribute__((ext_vector_type(4)));

__global__ void k_zero_i(int* __restrict__ p, int m) {
    int i = blockIdx.x * TPB + threadIdx.x;
    if (i < m) p[i] = 0;
}

// global per-bucket histogram (LDS-staged)
__global__ __launch_bounds__(TPB) void k_bhist(const int* __restrict__ dst,
                                               int* __restrict__ bcnt, int e, int nb) {
    __shared__ int h[MAXB];
    for (int i = threadIdx.x; i < MAXB; i += TPB) h[i] = 0;
    __syncthreads();
    int stride = gridDim.x * TPB;
    for (int i = blockIdx.x * TPB + threadIdx.x; i < e; i += stride)
        atomicAdd(&h[dst[i] >> TSH], 1);
    __syncthreads();
    for (int i = threadIdx.x; i < nb; i += TPB)
        if (h[i]) atomicAdd(&bcnt[i], h[i]);
}

// single-block exclusive scan of bucket counts -> bstart, init bcursor
__global__ void k_bscan(const int* __restrict__ bcnt, int* __restrict__ bstart,
                        int* __restrict__ bcursor, int nb) {
    __shared__ int buf[2][MAXB];
    int t = threadIdx.x;            // 512 threads
    int v = (t < nb) ? bcnt[t] : 0;
    buf[0][t] = v;
    __syncthreads();
    int cur = 0;
#pragma unroll
    for (int off = 1; off < MAXB; off <<= 1) {
        int nv = buf[cur][t] + (t >= off ? buf[cur][t - off] : 0);
        buf[cur ^ 1][t] = nv;
        __syncthreads();
        cur ^= 1;
    }
    int excl = buf[cur][t] - v;
    if (t < nb) { bstart[t] = excl; bcursor[t] = excl; }
    if (t == nb - 1) bstart[nb] = excl + v;
}

// bucket scatter: contiguous runs into bedges, packed (local_dst<<18)|src
__global__ __launch_bounds__(1024) void k_bscatter(const int* __restrict__ src,
                                                   const int* __restrict__ dst,
                                                   int* __restrict__ bcursor,
                                                   uint32_t* __restrict__ bedges,
                                                   int e, int chunk) {
    __shared__ int hcnt[MAXB];
    __shared__ int hbase[MAXB];
    __shared__ int hpos[MAXB];
    int t = threadIdx.x;
    for (int i = t; i < MAXB; i += 1024) { hcnt[i] = 0; hpos[i] = 0; }
    __syncthreads();

    int e0 = blockIdx.x * chunk;
    int e1 = min(e0 + chunk, e);

    for (int i = e0 + t; i < e1; i += 1024)
        atomicAdd(&hcnt[dst[i] >> TSH], 1);
    __syncthreads();
    for (int i = t; i < MAXB; i += 1024)
        if (hcnt[i]) hbase[i] = atomicAdd(&bcursor[i], hcnt[i]);
    __syncthreads();
    for (int i = e0 + t; i < e1; i += 1024) {
        int d = dst[i];
        int b = d >> TSH;
        int lp = atomicAdd(&hpos[b], 1);
        bedges[hbase[b] + lp] = ((uint32_t)(d & (TILE - 1)) << 18) | (uint32_t)src[i];
    }
}

// per-bucket counting sort: bedges segment -> csr (src only, exact dst order).
// Also emits node_start[d] and dis[d].
__global__ __launch_bounds__(1024) void k_sort(const uint32_t* __restrict__ bedges,
                                               const int* __restrict__ bstart,
                                               uint32_t* __restrict__ csr,
                                               int* __restrict__ node_start,
                                               float* __restrict__ dis, int n) {
    __shared__ int hist[TILE];
    __shared__ int sb[2][TILE];
    __shared__ int curp[TILE];
    int t = threadIdx.x;            // 1024 threads
    int b = blockIdx.x;
    int s0 = bstart[b], s1 = bstart[b + 1];

    if (t < TILE) hist[t] = 0;
    __syncthreads();
    for (int i = s0 + t; i < s1; i += 1024)
        atomicAdd(&hist[bedges[i] >> 18], 1);
    __syncthreads();

    if (t < TILE) sb[0][t] = hist[t];
    __syncthreads();
    int cur = 0;
#pragma unroll
    for (int off = 1; off < TILE; off <<= 1) {
        if (t < TILE) {
            int nv = sb[cur][t] + (t >= off ? sb[cur][t - off] : 0);
            sb[cur ^ 1][t] = nv;
        }
        __syncthreads();
        cur ^= 1;
    }
    if (t < TILE) {
        int ex = sb[cur][t] - hist[t];          // exclusive
        curp[t] = ex;
        int d = (b << TSH) + t;
        if (d <= n) node_start[d] = s0 + ex;
        if (d < n)  dis[d] = rsqrtf((float)hist[t] + 1.0f);
    }
    __syncthreads();

    for (int i = s0 + t; i < s1; i += 1024) {
        uint32_t p = bedges[i];
        int ld = (int)(p >> 18);
        int pos = atomicAdd(&curp[ld], 1);
        csr[s0 + pos] = p & 0x3FFFFu;
    }
}

// h1w = fp16( (x @ W1) * dis[row] ).
// W1 in LDS [k][lane] (conflict-free). 8 groups x 8 rows per block;
// per k4: 4 ds_read_b32 feed 32 FMA4s (8 rows in flight). x loads nontemporal.
__global__ __launch_bounds__(TPB) void k_gemm1h(const float* __restrict__ x,
                                                const float* __restrict__ W1,
                                                const float* __restrict__ dis,
                                                __half* __restrict__ h1w, int n) {
    __shared__ float w[128 * 32];
    for (int i = threadIdx.x; i < 128 * 32; i += TPB) w[i] = W1[i];
    __syncthreads();

    int lane = threadIdx.x & 31;
    int g    = threadIdx.x >> 5;
    int base = blockIdx.x * 64 + g * 8;
    if (base >= n) return;

    if (base + 7 < n) {
        float a0 = 0.f, a1 = 0.f, a2 = 0.f, a3 = 0.f;
        float a4 = 0.f, a5 = 0.f, a6 = 0.f, a7 = 0.f;
        const f4v* xr = (const f4v*)(x + (size_t)base * 128);
#pragma unroll
        for (int k4 = 0; k4 < 32; ++k4) {
            f4v v0 = __builtin_nontemporal_load(xr + 0 * 32 + k4);
            f4v v1 = __builtin_nontemporal_load(xr + 1 * 32 + k4);
            f4v v2 = __builtin_nontemporal_load(xr + 2 * 32 + k4);
            f4v v3 = __builtin_nontemporal_load(xr + 3 * 32 + k4);
            f4v v4 = __builtin_nontemporal_load(xr + 4 * 32 + k4);
            f4v v5 = __builtin_nontemporal_load(xr + 5 * 32 + k4);
            f4v v6 = __builtin_nontemporal_load(xr + 6 * 32 + k4);
            f4v v7 = __builtin_nontemporal_load(xr + 7 * 32 + k4);
            float w0 = w[(k4 * 4 + 0) * 32 + lane];
            float w1 = w[(k4 * 4 + 1) * 32 + lane];
            float w2 = w[(k4 * 4 + 2) * 32 + lane];
            float w3 = w[(k4 * 4 + 3) * 32 + lane];
            a0 = fmaf(v0[0], w0, a0); a0 = fmaf(v0[1], w1, a0); a0 = fmaf(v0[2], w2, a0); a0 = fmaf(v0[3], w3, a0);
            a1 = fmaf(v1[0], w0, a1); a1 = fmaf(v1[1], w1, a1); a1 = fmaf(v1[2], w2, a1); a1 = fmaf(v1[3], w3, a1);
            a2 = fmaf(v2[0], w0, a2); a2 = fmaf(v2[1], w1, a2); a2 = fmaf(v2[2], w2, a2); a2 = fmaf(v2[3], w3, a2);
            a3 = fmaf(v3[0], w0, a3); a3 = fmaf(v3[1], w1, a3); a3 = fmaf(v3[2], w2, a3); a3 = fmaf(v3[3], w3, a3);
            a4 = fmaf(v4[0], w0, a4); a4 = fmaf(v4[1], w1, a4); a4 = fmaf(v4[2], w2, a4); a4 = fmaf(v4[3], w3, a4);
            a5 = fmaf(v5[0], w0, a5); a5 = fmaf(v5[1], w1, a5); a5 = fmaf(v5[2], w2, a5); a5 = fmaf(v5[3], w3, a5);
            a6 = fmaf(v6[0], w0, a6); a6 = fmaf(v6[1], w1, a6); a6 = fmaf(v6[2], w2, a6); a6 = fmaf(v6[3], w3, a6);
            a7 = fmaf(v7[0], w0, a7); a7 = fmaf(v7[1], w1, a7); a7 = fmaf(v7[2], w2, a7); a7 = fmaf(v7[3], w3, a7);
        }
        h1w[(size_t)(base + 0) * 32 + lane] = __float2half(a0 * dis[base + 0]);
        h1w[(size_t)(base + 1) * 32 + lane] = __float2half(a1 * dis[base + 1]);
        h1w[(size_t)(base + 2) * 32 + lane] = __float2half(a2 * dis[base + 2]);
        h1w[(size_t)(base + 3) * 32 + lane] = __float2half(a3 * dis[base + 3]);
        h1w[(size_t)(base + 4) * 32 + lane] = __float2half(a4 * dis[base + 4]);
        h1w[(size_t)(base + 5) * 32 + lane] = __float2half(a5 * dis[base + 5]);
        h1w[(size_t)(base + 6) * 32 + lane] = __float2half(a6 * dis[base + 6]);
        h1w[(size_t)(base + 7) * 32 + lane] = __float2half(a7 * dis[base + 7]);
    } else {
        for (int rr = 0; rr < 8; ++rr) {
            int row = base + rr;
            if (row >= n) break;
            const f4v* x0 = (const f4v*)(x + (size_t)row * 128);
            float a = 0.f;
#pragma unroll
            for (int k4 = 0; k4 < 32; ++k4) {
                f4v v = x0[k4];
                a = fmaf(v[0], w[(k4 * 4 + 0) * 32 + lane], a);
                a = fmaf(v[1], w[(k4 * 4 + 1) * 32 + lane], a);
                a = fmaf(v[2], w[(k4 * 4 + 2) * 32 + lane], a);
                a = fmaf(v[3], w[(k4 * 4 + 3) * 32 + lane], a);
            }
            h1w[(size_t)row * 32 + lane] = __float2half(a * dis[row]);
        }
    }
}

// Layer1 gather: lane = channel-pair (half2), two 16-lane halves take even/odd
// edge slots -> 16 edges in flight per group. Fused bias/relu/dropout/W2.
__global__ __launch_bounds__(TPB) void k_gather1(const int* __restrict__ node_start,
                                                 const uint32_t* __restrict__ csr,
                                                 const float* __restrict__ dis,
                                                 const __half* __restrict__ h1w,
                                                 const float* __restrict__ b1,
                                                 const float* __restrict__ drop_u,
                                                 const float* __restrict__ W2,
                                                 float* __restrict__ hw2, int n) {
    int t = blockIdx.x * TPB + threadIdx.x;
    int d = t >> 5, c = t & 31;
    if (d >= n) return;
    int half = c >> 4;           // edge-slot parity
    int k2   = (c & 15) << 1;    // channel pair base

    int e  = node_start[d];
    int e1 = node_start[d + 1];

    float ax = 0.f, ay = 0.f;
    for (; e + 15 < e1; e += 16) {
        uint32_t s[8];
#pragma unroll
        for (int u = 0; u < 8; ++u)
            s[u] = __builtin_nontemporal_load(&csr[e + 2 * u + half]);
        __half2 h[8];
#pragma unroll
        for (int u = 0; u < 8; ++u)
            h[u] = *(const __half2*)&h1w[(size_t)s[u] * 32 + k2];
#pragma unroll
        for (int u = 0; u < 8; ++u) {
            float2 f = __half22float2(h[u]);
            ax += f.x; ay += f.y;
        }
    }
    for (; e + 1 < e1; e += 2) {
        uint32_t s = __builtin_nontemporal_load(&csr[e + half]);
        float2 f = __half22float2(*(const __half2*)&h1w[(size_t)s * 32 + k2]);
        ax += f.x; ay += f.y;
    }
    if (e < e1 && half == 0) {
        uint32_t s = __builtin_nontemporal_load(&csr[e]);
        float2 f = __half22float2(*(const __half2*)&h1w[(size_t)s * 32 + k2]);
        ax += f.x; ay += f.y;
    }
    ax += __shfl_xor(ax, 16, 32);
    ay += __shfl_xor(ay, 16, 32);

    float dd = dis[d];
    float2 s2 = __half22float2(*(const __half2*)&h1w[(size_t)d * 32 + k2]);
    f2v du = __builtin_nontemporal_load((const f2v*)&drop_u[(size_t)d * 32 + k2]);
    float vx = dd * (ax + s2.x) + b1[k2];
    float vy = dd * (ay + s2.y) + b1[k2 + 1];
    vx = fmaxf(vx, 0.f); vy = fmaxf(vy, 0.f);
    vx = (du[0] > 0.5f) ? vx * 2.f : 0.f;
    vy = (du[1] > 0.5f) ? vy * 2.f : 0.f;

    float p0 = vx * W2[k2 * 2 + 0] + vy * W2[k2 * 2 + 2];
    float p1 = vx * W2[k2 * 2 + 1] + vy * W2[k2 * 2 + 3];
#pragma unroll
    for (int off = 8; off >= 1; off >>= 1) {
        p0 += __shfl_xor(p0, off, 32);
        p1 += __shfl_xor(p1, off, 32);
    }
    if (c == 0) {
        float2 o; o.x = p0 * dd; o.y = p1 * dd;
        ((float2*)hw2)[d] = o;
    }
}

// Layer2 gather: out[d] = dis[d]*(sum_s hw2[s] + hw2[d]) + b2
__global__ __launch_bounds__(TPB) void k_gather2(const int* __restrict__ node_start,
                                                 const uint32_t* __restrict__ csr,
                                                 const float* __restrict__ dis,
                                                 const float* __restrict__ hw2,
                                                 const float* __restrict__ b2,
                                                 float* __restrict__ out, int n) {
    int t = blockIdx.x * TPB + threadIdx.x;
    int d = t >> 5, lane = t & 31;
    if (d >= n) return;

    int e0 = node_start[d];
    int e1 = node_start[d + 1];

    float a0 = 0.0f, a1 = 0.0f;
    for (int e = e0 + lane; e < e1; e += 32) {
        uint32_t s = __builtin_nontemporal_load(&csr[e]);
        float2 hv = ((const float2*)hw2)[s];
        a0 += hv.x;
        a1 += hv.y;
    }
#pragma unroll
    for (int off = 16; off >= 1; off >>= 1) {
        a0 += __shfl_xor(a0, off, 32);
        a1 += __shfl_xor(a1, off, 32);
    }
    if (lane == 0) {
        float dd = dis[d];
        float2 hv = ((const float2*)hw2)[d];
        out[(size_t)d * 2 + 0] = dd * (a0 + hv.x) + b2[0];
        out[(size_t)d * 2 + 1] = dd * (a1 + hv.y) + b2[1];
    }
}

extern "C" void kernel_launch(void* const* d_in, const int* in_sizes, int n_in,
                              void* d_out, int out_size, void* d_ws, size_t ws_size,
                              hipStream_t stream) {
    const float* x     = (const float*)d_in[0];
    const int*   ei    = (const int*)d_in[1];
    const float* W1    = (const float*)d_in[2];
    const float* b1    = (const float*)d_in[3];
    const float* W2    = (const float*)d_in[4];
    const float* b2    = (const float*)d_in[5];
    const float* dropu = (const float*)d_in[6];
    float* out = (float*)d_out;

    const int N = in_sizes[0] / 128;
    const int E = in_sizes[1] / 2;
    const int* src = ei;
    const int* dst = ei + E;

    const int NB = (N + TILE - 1) >> TSH;     // 391 for N=200000

    // ws: dis f32[N] | hw2 f32[2N] | node_start i32[N+1] | bcnt i32[MAXB] |
    //     bstart i32[MAXB+1] | bcursor i32[MAXB] | bedges u32[E] | csr u32[E] |
    //     h1w fp16[32N]
    float* dis = (float*)d_ws;
    float* hw2 = dis + N;
    int* node_start = (int*)(hw2 + (size_t)N * 2);
    int* bcnt    = node_start + (N + 1);
    int* bstart  = bcnt + MAXB;
    int* bcursor = bstart + (MAXB + 1);
    uint32_t* bedges = (uint32_t*)(bcursor + MAXB);
    uint32_t* csr    = bedges + E;
    __half* h1w = (__half*)(csr + E);

    const int chunk = (E + NB - 1) / NB;
    const int gG = (N * 32 + TPB - 1) / TPB;  // 32 lanes per node

    k_zero_i  <<<(MAXB + TPB - 1) / TPB, TPB, 0, stream>>>(bcnt, MAXB);
    k_bhist   <<<1024, TPB, 0, stream>>>(dst, bcnt, E, NB);
    k_bscan   <<<1, MAXB, 0, stream>>>(bcnt, bstart, bcursor, NB);
    k_bscatter<<<NB, 1024, 0, stream>>>(src, dst, bcursor, bedges, E, chunk);
    k_sort    <<<NB, 1024, 0, stream>>>(bedges, bstart, csr, node_start, dis, N);
    k_gemm1h  <<<(N + 63) / 64, TPB, 0, stream>>>(x, W1, dis, h1w, N);
    k_gather1 <<<gG, TPB, 0, stream>>>(node_start, csr, dis, h1w, b1, dropu, W2, hw2, N);
    k_gather2 <<<gG, TPB, 0, stream>>>(node_start, csr, dis, hw2, b2, out, N);
}